// Round 1
// baseline (205.287 us; speedup 1.0000x reference)
//
#include <hip/hip_runtime.h>
#include <math.h>

#define NN 8192
#define CC 4096
#define SLOTS 64
#define BLK 256

// out = sum_c cnt_c * value_c / (N * (N/NUM_POS)) ; NUM_POS=4
#define SCALE (4.0f / (8192.0f * 8192.0f))

__global__ void init_kernel(int* __restrict__ counts, float* __restrict__ out) {
    int i = blockIdx.x * blockDim.x + threadIdx.x;
    if (i < CC) counts[i] = 0;
    if (i == 0) out[0] = 0.0f;
}

__global__ void build_index(const int* __restrict__ label,
                            int* __restrict__ counts,
                            int* __restrict__ lists) {
    int i = blockIdx.x * blockDim.x + threadIdx.x;
    if (i < NN) {
        int lab = label[i];
        int pos = atomicAdd(&counts[lab], 1);
        if (pos < SLOTS) lists[lab * SLOTS + pos] = i;
    }
}

// One block per class c. 256 threads; thread t owns columns j*1024 + t*4 + l
// (j in [0,4), l in [0,4)) -> float4 coalesced loads, 16 KB row per 4 iters.
__global__ __launch_bounds__(BLK) void class_loss(const float* __restrict__ feat,
                                                  const int* __restrict__ counts,
                                                  const int* __restrict__ lists,
                                                  float* __restrict__ out) {
    int c = blockIdx.x;
    int cnt = counts[c];
    if (cnt == 0) return;  // class never appears; uniform across block

    int t = threadIdx.x;
    float4 acc[4];
    #pragma unroll
    for (int j = 0; j < 4; ++j) acc[j] = make_float4(0.f, 0.f, 0.f, 0.f);

    int m = cnt < SLOTS ? cnt : SLOTS;
    for (int k = 0; k < m; ++k) {
        int r = lists[c * SLOTS + k];
        const float4* rowp = (const float4*)(feat + (size_t)r * CC);
        #pragma unroll
        for (int j = 0; j < 4; ++j) {
            float4 v = rowp[j * 256 + t];
            acc[j].x += v.x; acc[j].y += v.y; acc[j].z += v.z; acc[j].w += v.w;
        }
    }

    float inv = 1.0f / (float)cnt;
    float vals[16];
    #pragma unroll
    for (int j = 0; j < 4; ++j) {
        vals[j * 4 + 0] = acc[j].x * inv;
        vals[j * 4 + 1] = acc[j].y * inv;
        vals[j * 4 + 2] = acc[j].z * inv;
        vals[j * 4 + 3] = acc[j].w * inv;
    }

    __shared__ float s_red[4];
    __shared__ float s_bcast;
    __shared__ float s_vc;

    // --- block max ---
    float wm = vals[0];
    #pragma unroll
    for (int j = 1; j < 16; ++j) wm = fmaxf(wm, vals[j]);
    #pragma unroll
    for (int off = 32; off > 0; off >>= 1) wm = fmaxf(wm, __shfl_down(wm, off, 64));
    int lane = t & 63, wv = t >> 6;
    if (lane == 0) s_red[wv] = wm;
    __syncthreads();
    if (t == 0) s_bcast = fmaxf(fmaxf(s_red[0], s_red[1]), fmaxf(s_red[2], s_red[3]));
    __syncthreads();
    float M = s_bcast;

    // --- block sum of exp(v - M) ---
    float se = 0.f;
    #pragma unroll
    for (int j = 0; j < 16; ++j) se += expf(vals[j] - M);
    #pragma unroll
    for (int off = 32; off > 0; off >>= 1) se += __shfl_down(se, off, 64);
    if (lane == 0) s_red[wv] = se;

    // owner thread deposits v at column c: col = j*1024 + t*4 + l
    if (t == ((c & 1023) >> 2)) s_vc = vals[((c >> 10) << 2) | (c & 3)];
    __syncthreads();

    if (t == 0) {
        float S = s_red[0] + s_red[1] + s_red[2] + s_red[3];
        float value = M + logf(S) - s_vc;
        atomicAdd(out, (float)cnt * value * SCALE);
    }
}

extern "C" void kernel_launch(void* const* d_in, const int* in_sizes, int n_in,
                              void* d_out, int out_size, void* d_ws, size_t ws_size,
                              hipStream_t stream) {
    const float* feat = (const float*)d_in[0];
    const int* label = (const int*)d_in[1];
    float* out = (float*)d_out;

    int* counts = (int*)d_ws;            // CC ints
    int* lists = counts + CC;            // CC * SLOTS ints

    init_kernel<<<(CC + BLK - 1) / BLK, BLK, 0, stream>>>(counts, out);
    build_index<<<(NN + BLK - 1) / BLK, BLK, 0, stream>>>(label, counts, lists);
    class_loss<<<CC, BLK, 0, stream>>>(feat, counts, lists, out);
}

// Round 2
// 201.584 us; speedup vs baseline: 1.0184x; 1.0184x over previous
//
#include <hip/hip_runtime.h>
#include <math.h>

#define NN 8192
#define CC 4096
#define SLOTS 64
#define BLK 256

// out = sum_c cnt_c * value_c * NUM_POS / N^2 ; NUM_POS=4, N=8192
#define SCALE (4.0f / (8192.0f * 8192.0f))

__global__ void init_kernel(int* __restrict__ counts) {
    int i = blockIdx.x * blockDim.x + threadIdx.x;
    if (i < CC) counts[i] = 0;
}

__global__ void build_index(const int* __restrict__ label,
                            int* __restrict__ counts,
                            int* __restrict__ lists) {
    int i = blockIdx.x * blockDim.x + threadIdx.x;
    if (i < NN) {
        int lab = label[i];
        int pos = atomicAdd(&counts[lab], 1);
        if (pos < SLOTS) lists[lab * SLOTS + pos] = i;
    }
}

// One block per class c. 256 threads; thread t owns columns j*1024 + t*4 + l.
// Row list staged to LDS up-front so all row loads have full MLP.
__global__ __launch_bounds__(BLK) void class_loss(const float* __restrict__ feat,
                                                  const int* __restrict__ counts,
                                                  const int* __restrict__ lists,
                                                  float* __restrict__ value) {
    int c = blockIdx.x;
    int t = threadIdx.x;

    __shared__ int s_cnt;
    __shared__ int s_rows[SLOTS];
    if (t == 0) s_cnt = counts[c];
    if (t < SLOTS) s_rows[t] = lists[c * SLOTS + t];  // in-bounds; junk beyond cnt unused
    __syncthreads();

    int cnt = s_cnt;
    if (cnt == 0) {
        if (t == 0) value[c] = 0.0f;
        return;
    }

    float4 acc[4];
    #pragma unroll
    for (int j = 0; j < 4; ++j) acc[j] = make_float4(0.f, 0.f, 0.f, 0.f);

    int m = cnt < SLOTS ? cnt : SLOTS;
    for (int k = 0; k < m; ++k) {
        const float4* rowp = (const float4*)(feat + (size_t)s_rows[k] * CC);
        #pragma unroll
        for (int j = 0; j < 4; ++j) {
            float4 v = rowp[j * 256 + t];
            acc[j].x += v.x; acc[j].y += v.y; acc[j].z += v.z; acc[j].w += v.w;
        }
    }

    float inv = 1.0f / (float)cnt;
    float vals[16];
    #pragma unroll
    for (int j = 0; j < 4; ++j) {
        vals[j * 4 + 0] = acc[j].x * inv;
        vals[j * 4 + 1] = acc[j].y * inv;
        vals[j * 4 + 2] = acc[j].z * inv;
        vals[j * 4 + 3] = acc[j].w * inv;
    }

    __shared__ float s_red[4];
    __shared__ float s_bcast;
    __shared__ float s_vc;

    // --- block max ---
    float wm = vals[0];
    #pragma unroll
    for (int j = 1; j < 16; ++j) wm = fmaxf(wm, vals[j]);
    #pragma unroll
    for (int off = 32; off > 0; off >>= 1) wm = fmaxf(wm, __shfl_down(wm, off, 64));
    int lane = t & 63, wv = t >> 6;
    if (lane == 0) s_red[wv] = wm;
    __syncthreads();
    if (t == 0) s_bcast = fmaxf(fmaxf(s_red[0], s_red[1]), fmaxf(s_red[2], s_red[3]));
    __syncthreads();
    float M = s_bcast;

    // --- block sum of exp(v - M) ---
    float se = 0.f;
    #pragma unroll
    for (int j = 0; j < 16; ++j) se += expf(vals[j] - M);
    #pragma unroll
    for (int off = 32; off > 0; off >>= 1) se += __shfl_down(se, off, 64);
    if (lane == 0) s_red[wv] = se;

    // owner thread deposits v at column c: col = j*1024 + t*4 + l
    if (t == ((c & 1023) >> 2)) s_vc = vals[((c >> 10) << 2) | (c & 3)];
    __syncthreads();

    if (t == 0) {
        float S = s_red[0] + s_red[1] + s_red[2] + s_red[3];
        float v = M + logf(S) - s_vc;
        value[c] = (float)cnt * v;   // plain store; no atomic
    }
}

__global__ __launch_bounds__(BLK) void finalize(const float* __restrict__ value,
                                                float* __restrict__ out) {
    int t = threadIdx.x;
    const float4* v4 = (const float4*)value;
    float s = 0.f;
    #pragma unroll
    for (int i = 0; i < CC / 4 / BLK; ++i) {
        float4 v = v4[i * BLK + t];
        s += v.x + v.y + v.z + v.w;
    }
    #pragma unroll
    for (int off = 32; off > 0; off >>= 1) s += __shfl_down(s, off, 64);
    __shared__ float s_red[4];
    int lane = t & 63, wv = t >> 6;
    if (lane == 0) s_red[wv] = s;
    __syncthreads();
    if (t == 0) out[0] = (s_red[0] + s_red[1] + s_red[2] + s_red[3]) * SCALE;
}

extern "C" void kernel_launch(void* const* d_in, const int* in_sizes, int n_in,
                              void* d_out, int out_size, void* d_ws, size_t ws_size,
                              hipStream_t stream) {
    const float* feat = (const float*)d_in[0];
    const int* label = (const int*)d_in[1];
    float* out = (float*)d_out;

    int* counts = (int*)d_ws;                    // CC ints
    int* lists = counts + CC;                    // CC * SLOTS ints
    float* value = (float*)(lists + CC * SLOTS); // CC floats

    init_kernel<<<(CC + BLK - 1) / BLK, BLK, 0, stream>>>(counts);
    build_index<<<(NN + BLK - 1) / BLK, BLK, 0, stream>>>(label, counts, lists);
    class_loss<<<CC, BLK, 0, stream>>>(feat, counts, lists, value);
    finalize<<<1, BLK, 0, stream>>>(value, out);
}